// Round 15
// baseline (19.751 us; speedup 1.0000x reference)
//
#include <hip/hip_runtime.h>
#include <hip/hip_bf16.h>

constexpr int L_LEN = 4096;
constexpr int CH = 8;          // channels
constexpr int S_SAMPLES = 256; // continuous start samples
constexpr int K_SAMP = 32;     // shapelet samples
constexpr int NSHAPE = 16;
constexpr int NB = 32;         // batch
constexpr int NPB = 4;                  // p values per block
constexpr int NPBLK = S_SAMPLES / NPB;  // 64 p-blocks
constexpr int THREADS = 512;            // b(32) x pl(4) x quarter(4, wave-uniform)

typedef _Float16 half2_t __attribute__((ext_vector_type(2)));
typedef float v4f __attribute__((ext_vector_type(4)));

__device__ __forceinline__ half2_t h2(unsigned u) {
    return __builtin_bit_cast(half2_t, u);
}
__device__ __forceinline__ unsigned pack2(float a, float b) {
    half2_t h; h[0] = (_Float16)a; h[1] = (_Float16)b;
    return __builtin_bit_cast(unsigned, h);
}
__device__ __forceinline__ float fdot2acc(half2_t a, half2_t b, float c) {
#if __has_builtin(__builtin_amdgcn_fdot2)
    return __builtin_amdgcn_fdot2(a, b, c, false);
#else
    return c + (float)a[0] * (float)b[0] + (float)a[1] * (float)b[1];
#endif
}

// path (B,L,C) f32 -> ws (L,B,C) f16-packed; 2 b-rows per thread for ILP.
// Streaming reads -> non-temporal; writes land in L2-resident 2MB buffer.
__global__ __launch_bounds__(256) void transpose_kernel(const v4f* __restrict__ src,
                                                        uint4* __restrict__ dst) {
    const int t  = blockIdx.x * 256 + threadIdx.x; // 65536 = L * B/2
    const int l  = t & (L_LEN - 1);
    const int b0 = t >> 12;                        // 0..15; handles b0 and b0+16
    const v4f f0 = __builtin_nontemporal_load(src + (b0 * L_LEN + l) * 2 + 0);
    const v4f f1 = __builtin_nontemporal_load(src + (b0 * L_LEN + l) * 2 + 1);
    const v4f g0 = __builtin_nontemporal_load(src + ((b0 + 16) * L_LEN + l) * 2 + 0);
    const v4f g1 = __builtin_nontemporal_load(src + ((b0 + 16) * L_LEN + l) * 2 + 1);
    uint4 o0, o1;
    o0.x = pack2(f0.x, f0.y);  o0.y = pack2(f0.z, f0.w);
    o0.z = pack2(f1.x, f1.y);  o0.w = pack2(f1.z, f1.w);
    o1.x = pack2(g0.x, g0.y);  o1.y = pack2(g0.z, g0.w);
    o1.z = pack2(g1.x, g1.y);  o1.w = pack2(g1.z, g1.w);
    dst[l * NB + b0]      = o0;
    dst[l * NB + b0 + 16] = o1;
}

// tid bits: [0:4]=b, [5:6]=pl, [7:8]=quarter (wave-uniform -> SGPR k0).
__global__ __launch_bounds__(THREADS, 8) void shapelet_min_kernel(
    const uint4* __restrict__ wst,       // (L, B, C/2) f16-packed path
    const float* __restrict__ lengths,   // (NSHAPE)
    const float* __restrict__ shapelets, // (NSHAPE, K, C)
    float* __restrict__ partial)         // (NSHAPE, NPBLK, NB)
{
    __shared__ uint4 shsm[K_SAMP];       // shapelet rows as 8 packed f16
    __shared__ float sred[4][NPB][NB];   // [quarter][pl][b]
    __shared__ float cand[2][NB];

    const int s   = blockIdx.y;
    const int tid = threadIdx.x;
    const int b   = tid & (NB - 1);
    const int pl  = (tid >> 5) & 3;
    const int quarter = __builtin_amdgcn_readfirstlane(tid >> 7); // wave-uniform
    const int p   = blockIdx.x * NPB + pl;         // 0..255

    if (tid < K_SAMP * CH / 2)
        ((unsigned*)shsm)[tid] = pack2(shapelets[s * K_SAMP * CH + 2 * tid],
                                       shapelets[s * K_SAMP * CH + 2 * tid + 1]);
    __syncthreads();

    const float len   = fminf(fmaxf(lengths[s], 0.01f), 512.0f);
    const float start = ((float)p / (float)(S_SAMPLES - 1)) * ((float)(L_LEN - 1) - len);
    const float step  = len * (1.0f / (float)(K_SAMP - 1));
    const int   k0    = quarter * (K_SAMP / 4);    // 0, 8, 16, 24 (SGPR)

    half2_t dprev0, dprev1, dprev2, dprev3;
    dprev0 = dprev1 = dprev2 = dprev3 = h2(0u);
    float sqprev = 0.f, segsum = 0.f;

    // one sample eval; kk = k0+i exactly (no clamp needed for executed iters)
    #define SAMPLE_EVAL(I)                                                    \
    {                                                                         \
        const int kk = k0 + (I);                                              \
        const float q = start + (float)kk * step;                             \
        const int idx = min((int)q, L_LEN - 2);                               \
        const float r = q - (float)idx;                                       \
        const int base = idx * NB + b;                                        \
        const uint4 A = wst[base];                                            \
        const uint4 C = wst[base + NB];                                       \
        const uint4 SH = shsm[kk];                                            \
        const _Float16 hr = (_Float16)r;                                      \
        half2_t rr; rr[0] = hr; rr[1] = hr;                                   \
        float sq = 0.f, dot = 0.f;                                            \
        {                                                                     \
            const half2_t P = h2(A.x), N = h2(C.x);                           \
            const half2_t d = P + rr * (N - P) - h2(SH.x);                    \
            sq  = fdot2acc(d, d, sq);  dot = fdot2acc(dprev0, d, dot);        \
            dprev0 = d;                                                       \
        }                                                                     \
        {                                                                     \
            const half2_t P = h2(A.y), N = h2(C.y);                           \
            const half2_t d = P + rr * (N - P) - h2(SH.y);                    \
            sq  = fdot2acc(d, d, sq);  dot = fdot2acc(dprev1, d, dot);        \
            dprev1 = d;                                                       \
        }                                                                     \
        {                                                                     \
            const half2_t P = h2(A.z), N = h2(C.z);                           \
            const half2_t d = P + rr * (N - P) - h2(SH.z);                    \
            sq  = fdot2acc(d, d, sq);  dot = fdot2acc(dprev2, d, dot);        \
            dprev2 = d;                                                       \
        }                                                                     \
        {                                                                     \
            const half2_t P = h2(A.w), N = h2(C.w);                           \
            const half2_t d = P + rr * (N - P) - h2(SH.w);                    \
            sq  = fdot2acc(d, d, sq);  dot = fdot2acc(dprev3, d, dot);        \
            dprev3 = d;                                                       \
        }                                                                     \
        if ((I) > 0) segsum += sqprev + dot + sq;                             \
        sqprev = sq;                                                          \
    }

    #pragma unroll
    for (int i = 0; i <= 7; ++i) SAMPLE_EVAL(i)

    if (quarter != 3) {        // uniform branch: q3 has only 7 segments
        SAMPLE_EVAL(8)
    }
    #undef SAMPLE_EVAL

    sred[quarter][pl][b] = segsum;     // 64 consecutive floats per wave: conflict-free
    __syncthreads();

    // integral per (pl, b), then min over the block's 4 p values
    if (tid < 128) {
        const int bb  = tid & (NB - 1);
        const int plx = (tid >> 5) & 3;            // wave0: plx 0,1; wave1: plx 2,3
        const float tot = sred[0][plx][bb] + sred[1][plx][bb] +
                          sred[2][plx][bb] + sred[3][plx][bb];
        float integral = len * (1.0f / (3.0f * (float)(K_SAMP - 1))) * tot;
        integral = fmaxf(integral, 0.0f);
        const float m1 = fminf(integral, __shfl_xor(integral, 32)); // pl pairs
        if ((tid & 32) == 0) cand[tid >> 6][bb] = m1;
    }
    __syncthreads();
    if (tid < NB)
        partial[(s * NPBLK + blockIdx.x) * NB + tid] = fminf(cand[0][tid], cand[1][tid]);
}

// one block per shapelet; 256 threads = b(32) x chunk(8)
__global__ __launch_bounds__(256) void shapelet_finalize_kernel(
    const float* __restrict__ partial, float* __restrict__ out)
{
    __shared__ float fred[8][NB];
    const int s     = blockIdx.x;
    const int tid   = threadIdx.x;
    const int b     = tid & (NB - 1);
    const int chunk = tid >> 5;                   // 0..7
    float m = 3.4e38f;
    #pragma unroll
    for (int j = 0; j < NPBLK / 8; ++j) {
        const int pb = chunk * (NPBLK / 8) + j;
        m = fminf(m, partial[(s * NPBLK + pb) * NB + b]);
    }
    fred[chunk][b] = m;
    __syncthreads();
    if (tid < NB) {
        float mm = fred[0][tid];
        #pragma unroll
        for (int j = 1; j < 8; ++j) mm = fminf(mm, fred[j][tid]);
        out[tid * NSHAPE + s] = sqrtf(fmaxf(mm, 1e-12f));
    }
}

extern "C" void kernel_launch(void* const* d_in, const int* in_sizes, int n_in,
                              void* d_out, int out_size, void* d_ws, size_t ws_size,
                              hipStream_t stream) {
    // inputs: times (L), path (B,L,C), lengths (NSHAPE), shapelets (NSHAPE,K,C)
    const float* path      = (const float*)d_in[1];
    const float* lengths   = (const float*)d_in[2];
    const float* shapelets = (const float*)d_in[3];
    float* out = (float*)d_out;

    uint4* wst     = (uint4*)d_ws;                                        // 2 MB
    float* partial = (float*)((char*)d_ws + (size_t)L_LEN * NB * 16);     // 4 KB

    transpose_kernel<<<L_LEN * NB / 2 / 256, 256, 0, stream>>>(
        (const v4f*)path, wst);
    dim3 grid(NPBLK, NSHAPE);
    shapelet_min_kernel<<<grid, THREADS, 0, stream>>>(wst, lengths, shapelets, partial);
    shapelet_finalize_kernel<<<NSHAPE, 256, 0, stream>>>(partial, out);
}